// Round 3
// baseline (450037.695 us; speedup 1.0000x reference)
//
#include <hip/hip_runtime.h>
#include <math.h>
#include <stddef.h>

#define B   32
#define TE  400
#define TD  800
#define ED  512
#define DD  80
#define LS  1024
#define G4  4096
#define UN  128
#define FLT 32
#define KW  31

#define NBLK 256
#define NTHR 512

__device__ __forceinline__ float fsig(float x){ return 1.f/(1.f+__expf(-x)); }
__device__ __forceinline__ float ftanh(float x){ return 1.f - 2.f/(__expf(2.f*x)+1.f); }

// ---------------- keys = values @ Wm : [B, TE, UN] (one-time) ----------------
__global__ void keys_kernel(const float* __restrict__ values, const float* __restrict__ Wm,
                            float* __restrict__ keys)
{
    int b  = blockIdx.x;
    int tg = blockIdx.y;
    int tid = threadIdx.x;    // 128
    __shared__ __align__(16) float v[8*512];
    const float* vb = values + (size_t)b*TE*ED + (size_t)tg*8*ED;
    for (int i = tid; i < 8*512; i += 128) v[i] = vb[i];
    __syncthreads();
    int u = tid;
    float acc[8];
#pragma unroll
    for (int i=0;i<8;i++) acc[i]=0.f;
    for (int k=0;k<ED;k++){
        float w = Wm[k*UN + u];
#pragma unroll
        for (int tt=0; tt<8; tt++) acc[tt] += v[tt*512 + k]*w;
    }
#pragma unroll
    for (int tt=0; tt<8; tt++)
        keys[(size_t)b*TE*UN + (size_t)(tg*8+tt)*UN + u] = acc[tt];
}

// ---------------- decT[t][k][b] = dec[b][t][k] (one-time transpose) ----------------
__global__ void dect_kernel(const float* __restrict__ dec, float* __restrict__ decT)
{
    int t = blockIdx.x; int tid = threadIdx.x; // 256
    __shared__ float tile[32*80];
    for (int o = tid; o < 32*80; o += 256){
        int b = o/80, k = o%80;
        tile[o] = dec[((size_t)b*TD + t)*DD + k];
    }
    __syncthreads();
    for (int o = tid; o < 80*32; o += 256){
        int k = o>>5, b = o&31;
        decT[((size_t)t*DD + k)*B + b] = tile[b*80 + k];
    }
}

// ---------------- grid barrier (proven in rounds 1-2) ----------------
__device__ __forceinline__ void gridbar(unsigned* cnt, unsigned* gen, unsigned& epoch)
{
    __syncthreads();
    if (threadIdx.x == 0){
        epoch++;
        unsigned prev = __hip_atomic_fetch_add(cnt, 1u, __ATOMIC_ACQ_REL, __HIP_MEMORY_SCOPE_AGENT);
        if (prev == (unsigned)(NBLK-1)){
            __hip_atomic_store(cnt, 0u, __ATOMIC_RELAXED, __HIP_MEMORY_SCOPE_AGENT);
            __hip_atomic_store(gen, epoch, __ATOMIC_RELEASE, __HIP_MEMORY_SCOPE_AGENT);
        } else {
            while (__hip_atomic_load(gen, __ATOMIC_RELAXED, __HIP_MEMORY_SCOPE_AGENT) < epoch)
                __builtin_amdgcn_s_sleep(2);
            (void)__hip_atomic_load(gen, __ATOMIC_ACQUIRE, __HIP_MEMORY_SCOPE_AGENT);
        }
    }
    __syncthreads();
}

__device__ __forceinline__ void fma16(float acc[4][4], const float4 w, const float4 x)
{
    const float wv[4] = {w.x, w.y, w.z, w.w};
    const float xv[4] = {x.x, x.y, x.z, x.w};
#pragma unroll
    for (int uu=0; uu<4; uu++)
#pragma unroll
        for (int bb=0; bb<4; bb++) acc[uu][bb] += wv[uu]*xv[bb];
}

// one k-iteration: 2x dwordx4 weight load + 1x b128 LDS x broadcast + 32 FMA
#define GEMM_J(WA, WB, SPLIT, K_, KK_) {                                        \
    const float* row_ = ((K_) < (SPLIT)) ? (WA) + (size_t)(K_)*G4               \
                                         : (WB) + (size_t)((K_)-(SPLIT))*G4;    \
    float4 w0q_ = *(const float4*)(row_ + gp*2048 + u0);                        \
    float4 w1q_ = *(const float4*)(row_ + gp*2048 + 1024 + u0);                 \
    float4 x4_  = *(const float4*)&xh[(KK_)*33 + q*4];                          \
    fma16(acc0, w0q_, x4_);                                                     \
    fma16(acc1, w1q_, x4_);                                                     \
}

// stage phase-1 x chunk [c0, c0+CK) : x = [dec(80) ; ctx(512) ; h0_prev(1024)]
#define STAGE1(C0, CK) {                                                        \
    for (int i = tid; i < (CK)*8; i += NTHR){                                   \
        int kk = i >> 3, bq = i & 7;                                            \
        int k = (C0) + kk;                                                      \
        float4 v;                                                               \
        if (k < 80){                                                            \
            v = *(const float4*)&decT[((size_t)t*80 + k)*32 + bq*4];            \
        } else if (k < 592){                                                    \
            if (t == 0){ v = make_float4(0.f,0.f,0.f,0.f); }                    \
            else {                                                              \
                v = *(const float4*)&ctxacc[(size_t)(par^1)*16384 + (size_t)(k-80)*32 + bq*4]; \
                float4 iv = *(const float4*)&invd[bq*4];                        \
                v.x*=iv.x; v.y*=iv.y; v.z*=iv.z; v.w*=iv.w;                     \
            }                                                                   \
        } else {                                                                \
            v = *(const float4*)&h0T[(size_t)(par^1)*32768 + (size_t)(k-592)*32 + bq*4]; \
        }                                                                       \
        *(float4*)&xh[kk*33 + bq*4] = v;                                        \
    } }

// stage phase-2 x chunk [c0, c0+512) : x = [h0_cur(1024) ; h1_prev(1024)]
#define STAGE2(C0) {                                                            \
    for (int i = tid; i < 512*8; i += NTHR){                                    \
        int kk = i >> 3, bq = i & 7;                                            \
        int k = (C0) + kk;                                                      \
        float4 v = (k < 1024)                                                   \
            ? *(const float4*)&h0T[(size_t)par*32768 + (size_t)k*32 + bq*4]     \
            : *(const float4*)&h1T[(size_t)(par^1)*32768 + (size_t)(k-1024)*32 + bq*4]; \
        *(float4*)&xh[kk*33 + bq*4] = v;                                        \
    } }

// in-LDS 32-way k-split reduce + bias + gate ; zp overlays xh (stride 513: conflict-free)
#define REDUCE_GATE(BIASP, CST, HDSTT, WRITE_H1N) {                             \
    __syncthreads();                                                            \
    _Pragma("unroll")                                                           \
    for (int gg=0; gg<2; gg++)                                                  \
    _Pragma("unroll")                                                           \
    for (int uu=0; uu<4; uu++){                                                 \
        int gu = (gp*2+gg)*4 + uu;                                              \
        float* ap = gg ? &acc1[uu][0] : &acc0[uu][0];                           \
        *(float4*)&zp[ks*513 + gu*32 + q*4] = make_float4(ap[0],ap[1],ap[2],ap[3]); \
    }                                                                           \
    __syncthreads();                                                            \
    {                                                                           \
        int gu = tid >> 5, b = tid & 31;                                        \
        float s = 0.f;                                                          \
        _Pragma("unroll")                                                       \
        for (int kq2=0; kq2<32; kq2++) s += zp[kq2*513 + gu*32 + b];            \
        zfin[gu*33 + b] = s + (BIASP)[(gu>>2)*1024 + u0 + (gu&3)];              \
    }                                                                           \
    __syncthreads();                                                            \
    if (tid < 128){                                                             \
        int u = tid >> 5, b = tid & 31;                                         \
        float zi = zfin[(0 +u)*33 + b];                                         \
        float zf = zfin[(4 +u)*33 + b];                                         \
        float zg = zfin[(8 +u)*33 + b];                                         \
        float zo = zfin[(12+u)*33 + b];                                         \
        float cn = fsig(zf)*(CST)[tid] + fsig(zi)*ftanh(zg);                    \
        float hn = fsig(zo)*ftanh(cn);                                          \
        (CST)[tid] = cn;                                                        \
        (HDSTT)[(size_t)par*32768 + (size_t)(u0+u)*32 + b] = hn;                \
        if (WRITE_H1N) h1N[(size_t)b*1024 + u0 + u] = hn;                       \
    } }

// ---------------- persistent recurrence kernel (streamed weights) ----------------
__global__ __launch_bounds__(NTHR, 2) void persist(
    const float* __restrict__ enc,   // values [B][TE][ED]
    const float* __restrict__ decT,  // [TD][80][32]
    const float* __restrict__ keys,  // [B][TE][UN]
    const float* __restrict__ W0, const float* __restrict__ U0, const float* __restrict__ b0v,
    const float* __restrict__ W1, const float* __restrict__ U1, const float* __restrict__ b1v,
    const float* __restrict__ Wq, const float* __restrict__ convk, const float* __restrict__ convb,
    const float* __restrict__ Wloc, const float* __restrict__ v_a, const float* __restrict__ b_a,
    float* __restrict__ h0T,   // [2][1024][32]
    float* __restrict__ h1T,   // [2][1024][32]
    float* __restrict__ h1N,   // [32][1024]  (k-contiguous copy of current h1)
    float* __restrict__ align_,// [B][TE]
    float* __restrict__ denomh,// [TD][B]
    float* __restrict__ ctxacc,// [2][512][32]
    unsigned* __restrict__ bar,
    float* __restrict__ c_out, float* __restrict__ e_out)
{
    __shared__ __align__(16) float xh[512*33];   // 67.6KB x-staging (stride 33) / zp overlay
    __shared__ float zfin[16*33];
    __shared__ float cst0[128], cst1[128];
    __shared__ __align__(16) float invd[32];
    __shared__ __align__(16) float h1s[1024];
    __shared__ float pqp[512];
    __shared__ float pqs[128];
    __shared__ float aw[96];
    __shared__ float fls[50*FLT];
    __shared__ float epart[128];
    __shared__ float alds[64];
    float* zp = xh;   // overlay: zp[32][513] = 16416 < 16896

    const int tid  = threadIdx.x;
    const int p    = blockIdx.x;
    const int ks   = tid >> 4;        // 0..31  in-block k-split
    const int slot = tid & 15;
    const int gp   = slot >> 3;       // gate-pair 0..1
    const int q    = slot & 7;        // batch-quad 0..7
    const int u0   = p*4;             // block owns units u0..u0+3 (cols g*1024+u0+uu)
    // attention mapping
    const int ab   = p >> 3;
    const int ach  = p & 7;
    const int t0a  = ach*50;

    if (tid < 128){ cst0[tid] = 0.f; cst1[tid] = 0.f; }
    unsigned epoch = 0;
    unsigned* cntp = bar;
    unsigned* genp = bar + 32;
    __syncthreads();

    for (int t = 0; t < TD; t++){
        const int par = t & 1;
        //======================= phase 1: z0 -> h0  (K = 1616) =======================
        if (tid < 32) invd[tid] = (t>0) ? 1.f/denomh[(size_t)(t-1)*32 + tid] : 0.f;
        __syncthreads();
        {
            float acc0[4][4], acc1[4][4];
#pragma unroll
            for (int uu=0;uu<4;uu++)
#pragma unroll
                for (int bb=0;bb<4;bb++){ acc0[uu][bb]=0.f; acc1[uu][bb]=0.f; }

            STAGE1(0, 512) __syncthreads();
#pragma unroll
            for (int j=0;j<16;j++){ int kk = ks+32*j; GEMM_J(W0,U0,592, kk, kk) }
            __syncthreads();
            STAGE1(512, 512) __syncthreads();
#pragma unroll
            for (int j=0;j<16;j++){ int kk = ks+32*j; GEMM_J(W0,U0,592, 512+kk, kk) }
            __syncthreads();
            STAGE1(1024, 512) __syncthreads();
#pragma unroll
            for (int j=0;j<16;j++){ int kk = ks+32*j; GEMM_J(W0,U0,592, 1024+kk, kk) }
            __syncthreads();
            STAGE1(1536, 80) __syncthreads();
            for (int j=0; ks+32*j < 80; j++){ int kk = ks+32*j; GEMM_J(W0,U0,592, 1536+kk, kk) }

            REDUCE_GATE(b0v, cst0, h0T, 0)
        }
        gridbar(cntp, genp, epoch);

        //======================= phase 2: z1 -> h1  (K = 2048) =======================
        if (t > 0){
            // fold a_{t-1} into cumulative alignment (block owns its 50-chunk)
            if (tid < 50){
                float idn = 1.f / denomh[(size_t)(t-1)*32 + ab];
                align_[(size_t)ab*TE + t0a + tid] +=
                    e_out[((size_t)ab*TD + (t-1))*TE + t0a + tid] * idn;
            }
            // write normalized c_out row t-1 and zero the consumed ctxacc buffer
            if (p < 32){
                float idn = 1.f / denomh[(size_t)(t-1)*32 + p];
                size_t ci = (size_t)(par^1)*16384 + (size_t)tid*32 + p;
                float v = ctxacc[ci];
                c_out[((size_t)p*TD + (t-1))*ED + tid] = v * idn;
                ctxacc[ci] = 0.f;
            }
        }
        {
            float acc0[4][4], acc1[4][4];
#pragma unroll
            for (int uu=0;uu<4;uu++)
#pragma unroll
                for (int bb=0;bb<4;bb++){ acc0[uu][bb]=0.f; acc1[uu][bb]=0.f; }

            STAGE2(0) __syncthreads();
#pragma unroll
            for (int j=0;j<16;j++){ int kk = ks+32*j; GEMM_J(W1,U1,1024, kk, kk) }
            __syncthreads();
            STAGE2(512) __syncthreads();
#pragma unroll
            for (int j=0;j<16;j++){ int kk = ks+32*j; GEMM_J(W1,U1,1024, 512+kk, kk) }
            __syncthreads();
            STAGE2(1024) __syncthreads();
#pragma unroll
            for (int j=0;j<16;j++){ int kk = ks+32*j; GEMM_J(W1,U1,1024, 1024+kk, kk) }
            __syncthreads();
            STAGE2(1536) __syncthreads();
#pragma unroll
            for (int j=0;j<16;j++){ int kk = ks+32*j; GEMM_J(W1,U1,1024, 1536+kk, kk) }

            REDUCE_GATE(b1v, cst1, h1T, 1)
        }
        gridbar(cntp, genp, epoch);

        //======================= phase 3: attention =======================
        // stage h1[ab] (k-contiguous) + alignment halo
        if (tid < 256) *(float4*)&h1s[tid*4] = *(const float4*)&h1N[(size_t)ab*1024 + tid*4];
        if (tid >= 256 && tid < 336){
            int j = tid - 256;
            int pp = t0a + j - 15;
            aw[j] = (pp >= 0 && pp < TE) ? align_[(size_t)ab*TE + pp] : 0.f;
        }
        __syncthreads();
        // pq partials (4-way k-split, coalesced Wq) + conv (independent)
        {
            int u = tid & 127, kq = tid >> 7;
            float s = 0.f;
#pragma unroll 8
            for (int k = kq*256; k < kq*256+256; k++)
                s += h1s[k] * Wq[(size_t)k*UN + u];
            pqp[kq*128 + u] = s;
        }
        for (int o = tid; o < 50*FLT; o += NTHR){
            int pos = o >> 5, fl = o & 31;
            float s = convb[fl];
#pragma unroll
            for (int k=0;k<KW;k++) s += aw[pos+k]*convk[k*FLT+fl];
            fls[o] = s;
        }
        __syncthreads();
        if (tid < 128) pqs[tid] = pqp[tid] + pqp[128+tid] + pqp[256+tid] + pqp[384+tid] + b_a[tid];
        __syncthreads();
        // energies
        for (int o = tid; o < 50*UN; o += NTHR){
            int pos = o >> 7, u = o & 127;
            float loc = 0.f;
            const float* fr = &fls[pos*FLT];
#pragma unroll
            for (int fl=0; fl<FLT; fl++) loc += fr[fl]*Wloc[fl*UN+u];
            float x = keys[((size_t)ab*TE + t0a + pos)*UN + u] + pqs[u] + loc;
            float val = v_a[u]*ftanh(x);
            val += __shfl_down(val, 32, 64);
            val += __shfl_down(val, 16, 64);
            val += __shfl_down(val,  8, 64);
            val += __shfl_down(val,  4, 64);
            val += __shfl_down(val,  2, 64);
            val += __shfl_down(val,  1, 64);
            if ((tid & 63) == 0) epart[o >> 6] = val;
        }
        __syncthreads();
        if (tid < 50){
            float e = epart[tid*2] + epart[tid*2+1];
            float ex = __expf(e);   // |e| small: max-free softmax safe
            e_out[((size_t)ab*TD + t)*TE + t0a + tid] = ex;   // unnormalized
            alds[tid] = ex;
        }
        __syncthreads();
        if (tid == 0){
            float s = 0.f;
#pragma unroll
            for (int i=0;i<50;i++) s += alds[i];
            atomicAdd(&denomh[(size_t)t*32 + ab], s);
        }
        {
            const float* vb = enc + ((size_t)ab*TE + t0a)*ED;
            float a2 = 0.f;
#pragma unroll 10
            for (int pp=0; pp<50; pp++) a2 += alds[pp]*vb[(size_t)pp*ED + tid];
            atomicAdd(&ctxacc[(size_t)par*16384 + (size_t)tid*32 + ab], a2);
        }
        gridbar(cntp, genp, epoch);
    }
}

// ---------------- final normalization ----------------
__global__ void norm_e_kernel(const float* __restrict__ denomh, float* __restrict__ e_out)
{
    size_t idx = (size_t)blockIdx.x*512 + threadIdx.x;
    int b = (int)(idx / ((size_t)TD*TE));
    int r = (int)(idx % ((size_t)TD*TE));
    int t = r / TE;
    e_out[idx] = e_out[idx] / denomh[(size_t)t*B + b];
}

__global__ void norm_c_last(const float* __restrict__ denomh, const float* __restrict__ ctxacc1,
                            float* __restrict__ c_out)
{
    int b = blockIdx.x; int d = threadIdx.x;   // 32 blocks x 512
    c_out[((size_t)b*TD + (TD-1))*ED + d] =
        ctxacc1[(size_t)d*32 + b] / denomh[(size_t)(TD-1)*B + b];
}

extern "C" void kernel_launch(void* const* d_in, const int* in_sizes, int n_in,
                              void* d_out, int out_size, void* d_ws, size_t ws_size,
                              hipStream_t stream)
{
    const float* enc   = (const float*)d_in[0];
    const float* dec   = (const float*)d_in[1];
    const float* Wm    = (const float*)d_in[2];
    const float* Wq    = (const float*)d_in[3];
    const float* convk = (const float*)d_in[4];
    const float* convb = (const float*)d_in[5];
    const float* Wloc  = (const float*)d_in[6];
    const float* v_a   = (const float*)d_in[7];
    const float* b_a   = (const float*)d_in[8];
    const float* W0    = (const float*)d_in[9];
    const float* U0    = (const float*)d_in[10];
    const float* b0    = (const float*)d_in[11];
    const float* W1    = (const float*)d_in[12];
    const float* U1    = (const float*)d_in[13];
    const float* b1    = (const float*)d_in[14];

    float* out   = (float*)d_out;
    float* c_out = out;                                  // [B, TD, ED]
    float* e_out = out + (size_t)B*TD*ED;                // [B, TD, TE]

    float* ws     = (float*)d_ws;
    float* h0T    = ws;                                  // 2*1024*32 = 65536
    float* h1T    = h0T + 65536;                         // 65536
    float* h1N    = h1T + 65536;                         // 32*1024 = 32768
    float* align_ = h1N + 32768;                         // 12800
    float* denomh = align_ + 12800;                      // 25600
    float* ctxacc = denomh + 25600;                      // 2*512*32 = 32768
    unsigned* bar = (unsigned*)(ctxacc + 32768);         // 64 uints
    float* keys   = (float*)(bar + 64);                  // B*TE*UN = 1638400
    float* decT   = keys + (size_t)B*TE*UN;              // TD*80*32 = 2048000

    // zero recurrent state + alignment + denominators + ctxacc + h1N + barrier
    hipMemsetAsync(ws, 0,
        (size_t)(65536 + 65536 + 32768 + 12800 + 25600 + 32768)*sizeof(float)
        + 64*sizeof(unsigned), stream);

    keys_kernel<<<dim3(B,50), 128, 0, stream>>>(enc, Wm, keys);
    dect_kernel<<<TD, 256, 0, stream>>>(dec, decT);

    persist<<<NBLK, NTHR, 0, stream>>>(enc, decT, keys,
                                       W0, U0, b0, W1, U1, b1,
                                       Wq, convk, convb, Wloc, v_a, b_a,
                                       h0T, h1T, h1N, align_, denomh, ctxacc, bar,
                                       c_out, e_out);

    norm_e_kernel<<<(B*TD*TE)/512, 512, 0, stream>>>(denomh, e_out);
    norm_c_last<<<32, 512, 0, stream>>>(denomh, ctxacc + 16384, c_out);
}

// Round 5
// 448581.982 us; speedup vs baseline: 1.0032x; 1.0032x over previous
//
#include <hip/hip_runtime.h>
#include <math.h>
#include <stddef.h>

#define B   32
#define TE  400
#define TD  800
#define ED  512
#define DD  80
#define LS  1024
#define G4  4096
#define UN  128
#define FLT 32
#define KW  31

#define NBLK 256
#define NTHR 512

__device__ __forceinline__ float fsig(float x){ return 1.f/(1.f+__expf(-x)); }
__device__ __forceinline__ float ftanh(float x){ return 1.f - 2.f/(__expf(2.f*x)+1.f); }

// ---------------- keys = values @ Wm : [B, TE, UN] (one-time) ----------------
__global__ void keys_kernel(const float* __restrict__ values, const float* __restrict__ Wm,
                            float* __restrict__ keys)
{
    int b  = blockIdx.x;
    int tg = blockIdx.y;
    int tid = threadIdx.x;    // 128
    __shared__ __align__(16) float v[8*512];
    const float* vb = values + (size_t)b*TE*ED + (size_t)tg*8*ED;
    for (int i = tid; i < 8*512; i += 128) v[i] = vb[i];
    __syncthreads();
    int u = tid;
    float acc[8];
#pragma unroll
    for (int i=0;i<8;i++) acc[i]=0.f;
    for (int k=0;k<ED;k++){
        float w = Wm[k*UN + u];
#pragma unroll
        for (int tt=0; tt<8; tt++) acc[tt] += v[tt*512 + k]*w;
    }
#pragma unroll
    for (int tt=0; tt<8; tt++)
        keys[(size_t)b*TE*UN + (size_t)(tg*8+tt)*UN + u] = acc[tt];
}

// ---------------- decT[t][k][b] = dec[b][t][k] (one-time transpose) ----------------
__global__ void dect_kernel(const float* __restrict__ dec, float* __restrict__ decT)
{
    int t = blockIdx.x; int tid = threadIdx.x; // 256
    __shared__ float tile[32*80];
    for (int o = tid; o < 32*80; o += 256){
        int b = o/80, k = o%80;
        tile[o] = dec[((size_t)b*TD + t)*DD + k];
    }
    __syncthreads();
    for (int o = tid; o < 80*32; o += 256){
        int k = o>>5, b = o&31;
        decT[((size_t)t*DD + k)*B + b] = tile[b*80 + k];
    }
}

// ---------------- grid barrier (proven rounds 1-3) ----------------
__device__ __forceinline__ void gridbar(unsigned* cnt, unsigned* gen, unsigned& epoch)
{
    __syncthreads();
    if (threadIdx.x == 0){
        epoch++;
        unsigned prev = __hip_atomic_fetch_add(cnt, 1u, __ATOMIC_ACQ_REL, __HIP_MEMORY_SCOPE_AGENT);
        if (prev == (unsigned)(NBLK-1)){
            __hip_atomic_store(cnt, 0u, __ATOMIC_RELAXED, __HIP_MEMORY_SCOPE_AGENT);
            __hip_atomic_store(gen, epoch, __ATOMIC_RELEASE, __HIP_MEMORY_SCOPE_AGENT);
        } else {
            while (__hip_atomic_load(gen, __ATOMIC_RELAXED, __HIP_MEMORY_SCOPE_AGENT) < epoch)
                __builtin_amdgcn_s_sleep(2);
            (void)__hip_atomic_load(gen, __ATOMIC_ACQUIRE, __HIP_MEMORY_SCOPE_AGENT);
        }
    }
    __syncthreads();
}

__device__ __forceinline__ void fma16(float acc[4][4], const float4 w, const float4 x)
{
    const float wv[4] = {w.x, w.y, w.z, w.w};
    const float xv[4] = {x.x, x.y, x.z, x.w};
#pragma unroll
    for (int uu=0; uu<4; uu++)
#pragma unroll
        for (int bb=0; bb<4; bb++) acc[uu][bb] += wv[uu]*xv[bb];
}

// one k-iteration: 2x dwordx4 weight load + 1x b128 LDS x broadcast + 32 FMA
#define GEMM_J(WA, WB, SPLIT, K_, KK_) {                                        \
    const float* row_ = ((K_) < (SPLIT)) ? (WA) + (size_t)(K_)*G4               \
                                         : (WB) + (size_t)((K_)-(SPLIT))*G4;    \
    float4 w0q_ = *(const float4*)(row_ + gp*2048 + u0);                        \
    float4 w1q_ = *(const float4*)(row_ + gp*2048 + 1024 + u0);                 \
    float4 x4_  = *(const float4*)&xh[(KK_)*33 + q*4];                          \
    fma16(acc0, w0q_, x4_);                                                     \
    fma16(acc1, w1q_, x4_);                                                     \
}

// stage phase-1 x chunk [c0, c0+CK) : x = [dec(80) ; ctx(512) ; h0_prev(1024)]
#define STAGE1(C0, CK) {                                                        \
    for (int i = tid; i < (CK)*8; i += NTHR){                                   \
        int kk = i >> 3, bq = i & 7;                                            \
        int k = (C0) + kk;                                                      \
        float4 v;                                                               \
        if (k < 80){                                                            \
            v = *(const float4*)&decT[((size_t)t*80 + k)*32 + bq*4];            \
        } else if (k < 592){                                                    \
            if (t == 0){ v = make_float4(0.f,0.f,0.f,0.f); }                    \
            else {                                                              \
                v = *(const float4*)&ctxacc[(size_t)(par^1)*16384 + (size_t)(k-80)*32 + bq*4]; \
                float4 iv = *(const float4*)&invd[bq*4];                        \
                v.x*=iv.x; v.y*=iv.y; v.z*=iv.z; v.w*=iv.w;                     \
            }                                                                   \
        } else {                                                                \
            v = *(const float4*)&h0T[(size_t)(par^1)*32768 + (size_t)(k-592)*32 + bq*4]; \
        }                                                                       \
        *(float4*)&xh[kk*33 + bq*4] = v;                                        \
    } }

// stage phase-2 x chunk [c0, c0+512) : x = [h0_cur(1024) ; h1_prev(1024)]
#define STAGE2(C0) {                                                            \
    for (int i = tid; i < 512*8; i += NTHR){                                    \
        int kk = i >> 3, bq = i & 7;                                            \
        int k = (C0) + kk;                                                      \
        float4 v = (k < 1024)                                                   \
            ? *(const float4*)&h0T[(size_t)par*32768 + (size_t)k*32 + bq*4]     \
            : *(const float4*)&h1T[(size_t)(par^1)*32768 + (size_t)(k-1024)*32 + bq*4]; \
        *(float4*)&xh[kk*33 + bq*4] = v;                                        \
    } }

// in-LDS 32-way k-split reduce + bias + gate ; zp overlays xh (stride 513: conflict-free)
#define REDUCE_GATE(BIASP, CST, HDSTT, WRITE_H1N) {                             \
    __syncthreads();                                                            \
    _Pragma("unroll")                                                           \
    for (int gg=0; gg<2; gg++)                                                  \
    _Pragma("unroll")                                                           \
    for (int uu=0; uu<4; uu++){                                                 \
        int gu = (gp*2+gg)*4 + uu;                                              \
        float* ap = gg ? &acc1[uu][0] : &acc0[uu][0];                           \
        *(float4*)&zp[ks*513 + gu*32 + q*4] = make_float4(ap[0],ap[1],ap[2],ap[3]); \
    }                                                                           \
    __syncthreads();                                                            \
    {                                                                           \
        int gu = tid >> 5, b = tid & 31;                                        \
        float s = 0.f;                                                          \
        _Pragma("unroll")                                                       \
        for (int kq2=0; kq2<32; kq2++) s += zp[kq2*513 + gu*32 + b];            \
        zfin[gu*33 + b] = s + (BIASP)[(gu>>2)*1024 + u0 + (gu&3)];              \
    }                                                                           \
    __syncthreads();                                                            \
    if (tid < 128){                                                             \
        int u = tid >> 5, b = tid & 31;                                         \
        float zi = zfin[(0 +u)*33 + b];                                         \
        float zf = zfin[(4 +u)*33 + b];                                         \
        float zg = zfin[(8 +u)*33 + b];                                         \
        float zo = zfin[(12+u)*33 + b];                                         \
        float cn = fsig(zf)*(CST)[tid] + fsig(zi)*ftanh(zg);                    \
        float hn = fsig(zo)*ftanh(cn);                                          \
        (CST)[tid] = cn;                                                        \
        (HDSTT)[(size_t)par*32768 + (size_t)(u0+u)*32 + b] = hn;                \
        if (WRITE_H1N) h1N[(size_t)b*1024 + u0 + u] = hn;                       \
    } }

// ---------------- persistent recurrence kernel (streamed weights, XCD-swizzled) -------
__global__ __launch_bounds__(NTHR, 2) void persist(
    const float* __restrict__ enc,   // values [B][TE][ED]
    const float* __restrict__ decT,  // [TD][80][32]
    const float* __restrict__ keys,  // [B][TE][UN]
    const float* __restrict__ W0, const float* __restrict__ U0, const float* __restrict__ b0v,
    const float* __restrict__ W1, const float* __restrict__ U1, const float* __restrict__ b1v,
    const float* __restrict__ Wq, const float* __restrict__ convk, const float* __restrict__ convb,
    const float* __restrict__ Wloc, const float* __restrict__ v_a, const float* __restrict__ b_a,
    float* __restrict__ h0T,   // [2][1024][32]
    float* __restrict__ h1T,   // [2][1024][32]
    float* __restrict__ h1N,   // [32][1024]
    float* __restrict__ align_,// [B][TE]
    float* __restrict__ denomh,// [TD][B]
    float* __restrict__ ctxacc,// [2][512][32]
    unsigned* __restrict__ bar,
    float* __restrict__ c_out, float* __restrict__ e_out)
{
    __shared__ __align__(16) float xh[512*33];   // x-staging (stride 33) / zp overlay
    __shared__ float zfin[16*33];
    __shared__ float cst0[128], cst1[128];
    __shared__ __align__(16) float invd[32];
    __shared__ __align__(16) float h1s[1024];
    __shared__ float pqp[512];
    __shared__ float pqs[128];
    __shared__ float aw[96];
    __shared__ float fls[50*FLT];
    __shared__ float epart[128];
    __shared__ float alds[64];
    float* zp = xh;   // overlay: zp[32][513] = 16416 < 16896

    const int tid  = threadIdx.x;
    const int p    = blockIdx.x;
    const int ks   = tid >> 4;        // 0..31  in-block k-split
    const int slot = tid & 15;
    const int gp   = slot >> 3;       // gate-pair 0..1
    const int q    = slot & 7;        // batch-quad 0..7
    // XCD-aware unit-group ownership: a 128B weight line covers 8 consecutive
    // unit-groups; ug = (p>>3) + 32*(p&7) makes all 8 sharers have the same
    // p&7 -> same XCD (round-robin dispatch) -> line fetched from HBM once,
    // served 7x from that XCD's L2. (Round 3 measured 8x HBM amplification
    // with u0 = p*4: 595 GB fetched.)
    const int ug   = (p>>3) + 32*(p&7);
    const int u0   = ug*4;            // block owns units u0..u0+3 (cols g*1024+u0+uu)
    // attention mapping (independent of u0)
    const int ab   = p >> 3;
    const int ach  = p & 7;
    const int t0a  = ach*50;

    if (tid < 128){ cst0[tid] = 0.f; cst1[tid] = 0.f; }
    unsigned epoch = 0;
    unsigned* cntp = bar;
    unsigned* genp = bar + 32;
    __syncthreads();

    for (int t = 0; t < TD; t++){
        const int par = t & 1;
        //======================= phase 1: z0 -> h0  (K = 1616) =======================
        if (tid < 32) invd[tid] = (t>0) ? 1.f/denomh[(size_t)(t-1)*32 + tid] : 0.f;
        __syncthreads();
        {
            float acc0[4][4], acc1[4][4];
#pragma unroll
            for (int uu=0;uu<4;uu++)
#pragma unroll
                for (int bb=0;bb<4;bb++){ acc0[uu][bb]=0.f; acc1[uu][bb]=0.f; }

            STAGE1(0, 512) __syncthreads();
#pragma unroll
            for (int j=0;j<16;j++){ int kk = ks+32*j; GEMM_J(W0,U0,592, kk, kk) }
            __syncthreads();
            STAGE1(512, 512) __syncthreads();
#pragma unroll
            for (int j=0;j<16;j++){ int kk = ks+32*j; GEMM_J(W0,U0,592, 512+kk, kk) }
            __syncthreads();
            STAGE1(1024, 512) __syncthreads();
#pragma unroll
            for (int j=0;j<16;j++){ int kk = ks+32*j; GEMM_J(W0,U0,592, 1024+kk, kk) }
            __syncthreads();
            STAGE1(1536, 80) __syncthreads();
            for (int j=0; ks+32*j < 80; j++){ int kk = ks+32*j; GEMM_J(W0,U0,592, 1536+kk, kk) }

            REDUCE_GATE(b0v, cst0, h0T, 0)
        }
        gridbar(cntp, genp, epoch);

        //======================= phase 2: z1 -> h1  (K = 2048) =======================
        if (t > 0){
            // fold a_{t-1} into cumulative alignment (block owns its 50-chunk)
            if (tid < 50){
                float idn = 1.f / denomh[(size_t)(t-1)*32 + ab];
                align_[(size_t)ab*TE + t0a + tid] +=
                    e_out[((size_t)ab*TD + (t-1))*TE + t0a + tid] * idn;
            }
            // write normalized c_out row t-1 and zero the consumed ctxacc buffer
            if (p < 32){
                float idn = 1.f / denomh[(size_t)(t-1)*32 + p];
                size_t ci = (size_t)(par^1)*16384 + (size_t)tid*32 + p;
                float v = ctxacc[ci];
                c_out[((size_t)p*TD + (t-1))*ED + tid] = v * idn;
                ctxacc[ci] = 0.f;
            }
        }
        {
            float acc0[4][4], acc1[4][4];
#pragma unroll
            for (int uu=0;uu<4;uu++)
#pragma unroll
                for (int bb=0;bb<4;bb++){ acc0[uu][bb]=0.f; acc1[uu][bb]=0.f; }

            STAGE2(0) __syncthreads();
#pragma unroll
            for (int j=0;j<16;j++){ int kk = ks+32*j; GEMM_J(W1,U1,1024, kk, kk) }
            __syncthreads();
            STAGE2(512) __syncthreads();
#pragma unroll
            for (int j=0;j<16;j++){ int kk = ks+32*j; GEMM_J(W1,U1,1024, 512+kk, kk) }
            __syncthreads();
            STAGE2(1024) __syncthreads();
#pragma unroll
            for (int j=0;j<16;j++){ int kk = ks+32*j; GEMM_J(W1,U1,1024, 1024+kk, kk) }
            __syncthreads();
            STAGE2(1536) __syncthreads();
#pragma unroll
            for (int j=0;j<16;j++){ int kk = ks+32*j; GEMM_J(W1,U1,1024, 1536+kk, kk) }

            REDUCE_GATE(b1v, cst1, h1T, 1)
        }
        gridbar(cntp, genp, epoch);

        //======================= phase 3: attention =======================
        if (tid < 256) *(float4*)&h1s[tid*4] = *(const float4*)&h1N[(size_t)ab*1024 + tid*4];
        if (tid >= 256 && tid < 336){
            int j = tid - 256;
            int pp = t0a + j - 15;
            aw[j] = (pp >= 0 && pp < TE) ? align_[(size_t)ab*TE + pp] : 0.f;
        }
        __syncthreads();
        {
            int u = tid & 127, kq = tid >> 7;
            float s = 0.f;
#pragma unroll 8
            for (int k = kq*256; k < kq*256+256; k++)
                s += h1s[k] * Wq[(size_t)k*UN + u];
            pqp[kq*128 + u] = s;
        }
        for (int o = tid; o < 50*FLT; o += NTHR){
            int pos = o >> 5, fl = o & 31;
            float s = convb[fl];
#pragma unroll
            for (int k=0;k<KW;k++) s += aw[pos+k]*convk[k*FLT+fl];
            fls[o] = s;
        }
        __syncthreads();
        if (tid < 128) pqs[tid] = pqp[tid] + pqp[128+tid] + pqp[256+tid] + pqp[384+tid] + b_a[tid];
        __syncthreads();
        for (int o = tid; o < 50*UN; o += NTHR){
            int pos = o >> 7, u = o & 127;
            float loc = 0.f;
            const float* fr = &fls[pos*FLT];
#pragma unroll
            for (int fl=0; fl<FLT; fl++) loc += fr[fl]*Wloc[fl*UN+u];
            float x = keys[((size_t)ab*TE + t0a + pos)*UN + u] + pqs[u] + loc;
            float val = v_a[u]*ftanh(x);
            val += __shfl_down(val, 32, 64);
            val += __shfl_down(val, 16, 64);
            val += __shfl_down(val,  8, 64);
            val += __shfl_down(val,  4, 64);
            val += __shfl_down(val,  2, 64);
            val += __shfl_down(val,  1, 64);
            if ((tid & 63) == 0) epart[o >> 6] = val;
        }
        __syncthreads();
        if (tid < 50){
            float e = epart[tid*2] + epart[tid*2+1];
            float ex = __expf(e);   // |e| small: max-free softmax safe
            e_out[((size_t)ab*TD + t)*TE + t0a + tid] = ex;   // unnormalized
            alds[tid] = ex;
        }
        __syncthreads();
        if (tid == 0){
            float s = 0.f;
#pragma unroll
            for (int i=0;i<50;i++) s += alds[i];
            atomicAdd(&denomh[(size_t)t*32 + ab], s);
        }
        {
            const float* vb = enc + ((size_t)ab*TE + t0a)*ED;
            float a2 = 0.f;
#pragma unroll 10
            for (int pp=0; pp<50; pp++) a2 += alds[pp]*vb[(size_t)pp*ED + tid];
            atomicAdd(&ctxacc[(size_t)par*16384 + (size_t)tid*32 + ab], a2);
        }
        gridbar(cntp, genp, epoch);
    }
}

// ---------------- final normalization ----------------
__global__ void norm_e_kernel(const float* __restrict__ denomh, float* __restrict__ e_out)
{
    size_t idx = (size_t)blockIdx.x*512 + threadIdx.x;
    int b = (int)(idx / ((size_t)TD*TE));
    int r = (int)(idx % ((size_t)TD*TE));
    int t = r / TE;
    e_out[idx] = e_out[idx] / denomh[(size_t)t*B + b];
}

__global__ void norm_c_last(const float* __restrict__ denomh, const float* __restrict__ ctxacc1,
                            float* __restrict__ c_out)
{
    int b = blockIdx.x; int d = threadIdx.x;   // 32 blocks x 512
    c_out[((size_t)b*TD + (TD-1))*ED + d] =
        ctxacc1[(size_t)d*32 + b] / denomh[(size_t)(TD-1)*B + b];
}

extern "C" void kernel_launch(void* const* d_in, const int* in_sizes, int n_in,
                              void* d_out, int out_size, void* d_ws, size_t ws_size,
                              hipStream_t stream)
{
    const float* enc   = (const float*)d_in[0];
    const float* dec   = (const float*)d_in[1];
    const float* Wm    = (const float*)d_in[2];
    const float* Wq    = (const float*)d_in[3];
    const float* convk = (const float*)d_in[4];
    const float* convb = (const float*)d_in[5];
    const float* Wloc  = (const float*)d_in[6];
    const float* v_a   = (const float*)d_in[7];
    const float* b_a   = (const float*)d_in[8];
    const float* W0    = (const float*)d_in[9];
    const float* U0    = (const float*)d_in[10];
    const float* b0    = (const float*)d_in[11];
    const float* W1    = (const float*)d_in[12];
    const float* U1    = (const float*)d_in[13];
    const float* b1    = (const float*)d_in[14];

    float* out   = (float*)d_out;
    float* c_out = out;                                  // [B, TD, ED]
    float* e_out = out + (size_t)B*TD*ED;                // [B, TD, TE]

    float* ws     = (float*)d_ws;
    float* h0T    = ws;                                  // 2*1024*32 = 65536
    float* h1T    = h0T + 65536;                         // 65536
    float* h1N    = h1T + 65536;                         // 32768
    float* align_ = h1N + 32768;                         // 12800
    float* denomh = align_ + 12800;                      // 25600
    float* ctxacc = denomh + 25600;                      // 32768
    unsigned* bar = (unsigned*)(ctxacc + 32768);         // 64 uints
    float* keys   = (float*)(bar + 64);                  // 1,638,400
    float* decT   = keys + (size_t)B*TE*UN;              // 2,048,000

    // zero recurrent state + alignment + denominators + ctxacc + barrier
    hipMemsetAsync(ws, 0,
        (size_t)(65536 + 65536 + 32768 + 12800 + 25600 + 32768)*sizeof(float)
        + 64*sizeof(unsigned), stream);

    keys_kernel<<<dim3(B,50), 128, 0, stream>>>(enc, Wm, keys);
    dect_kernel<<<TD, 256, 0, stream>>>(dec, decT);

    persist<<<NBLK, NTHR, 0, stream>>>(enc, decT, keys,
                                       W0, U0, b0, W1, U1, b1,
                                       Wq, convk, convb, Wloc, v_a, b_a,
                                       h0T, h1T, h1N, align_, denomh, ctxacc, bar,
                                       c_out, e_out);

    norm_e_kernel<<<(B*TD*TE)/512, 512, 0, stream>>>(denomh, e_out);
    norm_c_last<<<32, 512, 0, stream>>>(denomh, ctxacc + 16384, c_out);
}

// Round 7
// 87020.441 us; speedup vs baseline: 5.1716x; 5.1549x over previous
//
#include <hip/hip_runtime.h>
#include <math.h>
#include <stddef.h>

#define B   32
#define TE  400
#define TD  800
#define ED  512
#define DD  80
#define LS  1024
#define G4  4096
#define UN  128
#define FLT 32
#define KW  31

#define NBLK 256
#define NTHR 512

__device__ __forceinline__ float fsig(float x){ return 1.f/(1.f+__expf(-x)); }
__device__ __forceinline__ float ftanh(float x){ return 1.f - 2.f/(__expf(2.f*x)+1.f); }

// ---------------- keys = values @ Wm : [B, TE, UN] (one-time) ----------------
__global__ void keys_kernel(const float* __restrict__ values, const float* __restrict__ Wm,
                            float* __restrict__ keys)
{
    int b  = blockIdx.x;
    int tg = blockIdx.y;
    int tid = threadIdx.x;    // 128
    __shared__ __align__(16) float v[8*512];
    const float* vb = values + (size_t)b*TE*ED + (size_t)tg*8*ED;
    for (int i = tid; i < 8*512; i += 128) v[i] = vb[i];
    __syncthreads();
    int u = tid;
    float acc[8];
#pragma unroll
    for (int i=0;i<8;i++) acc[i]=0.f;
    for (int k=0;k<ED;k++){
        float w = Wm[k*UN + u];
#pragma unroll
        for (int tt=0; tt<8; tt++) acc[tt] += v[tt*512 + k]*w;
    }
#pragma unroll
    for (int tt=0; tt<8; tt++)
        keys[(size_t)b*TE*UN + (size_t)(tg*8+tt)*UN + u] = acc[tt];
}

// ---------------- grid barrier (proven rounds 1-5) ----------------
__device__ __forceinline__ void gridbar(unsigned* cnt, unsigned* gen, unsigned& epoch)
{
    __syncthreads();
    if (threadIdx.x == 0){
        epoch++;
        unsigned prev = __hip_atomic_fetch_add(cnt, 1u, __ATOMIC_ACQ_REL, __HIP_MEMORY_SCOPE_AGENT);
        if (prev == (unsigned)(NBLK-1)){
            __hip_atomic_store(cnt, 0u, __ATOMIC_RELAXED, __HIP_MEMORY_SCOPE_AGENT);
            __hip_atomic_store(gen, epoch, __ATOMIC_RELEASE, __HIP_MEMORY_SCOPE_AGENT);
        } else {
            while (__hip_atomic_load(gen, __ATOMIC_RELAXED, __HIP_MEMORY_SCOPE_AGENT) < epoch)
                __builtin_amdgcn_s_sleep(2);
            (void)__hip_atomic_load(gen, __ATOMIC_ACQUIRE, __HIP_MEMORY_SCOPE_AGENT);
        }
    }
    __syncthreads();
}

// thread owns cols ct*32 + cq*4 + i (i=0..3), batches bq*4 + j (j=0..3)
__device__ __forceinline__ void fma16(float acc[4][4], const float4 w, const float4 x)
{
    const float wv[4] = {w.x, w.y, w.z, w.w};
    const float xv[4] = {x.x, x.y, x.z, x.w};
#pragma unroll
    for (int i=0; i<4; i++)
#pragma unroll
        for (int j=0; j<4; j++) acc[i][j] += wv[i]*xv[j];
}

// stage phase-1 x chunk: absolute k in [KOFF, KOFF+CK) ; x = [dec(80);ctx(512);h0_prev(1024)]
// dec read directly (scalar gather, 80 rows only) - decT buffer dropped to fit 16MB ws
#define STAGE_PH1(KOFF, CK)                                                     \
    for (int i = tid; i < (CK)*8; i += NTHR){                                   \
        int kk = i >> 3, bq2 = i & 7;                                           \
        int k = (KOFF) + kk;                                                    \
        float4 v4;                                                              \
        if (k < 80){                                                            \
            int b0_ = bq2*4;                                                    \
            v4.x = dec[((size_t)(b0_+0)*TD + t)*DD + k];                        \
            v4.y = dec[((size_t)(b0_+1)*TD + t)*DD + k];                        \
            v4.z = dec[((size_t)(b0_+2)*TD + t)*DD + k];                        \
            v4.w = dec[((size_t)(b0_+3)*TD + t)*DD + k];                        \
        } else if (k < 592){                                                    \
            if (t == 0){ v4 = make_float4(0.f,0.f,0.f,0.f); }                   \
            else {                                                              \
                v4 = *(const float4*)&ctxacc[(size_t)(par^1)*16384 + (size_t)(k-80)*32 + bq2*4]; \
                float4 iv = *(const float4*)&invd[bq2*4];                       \
                v4.x*=iv.x; v4.y*=iv.y; v4.z*=iv.z; v4.w*=iv.w;                 \
            }                                                                   \
        } else {                                                                \
            v4 = *(const float4*)&h0T[(size_t)(par^1)*32768 + (size_t)(k-592)*32 + bq2*4]; \
        }                                                                       \
        *(float4*)&xh[kk*33 + bq2*4] = v4;                                      \
    }

// stage phase-2 x chunk: absolute k in [KOFF, KOFF+512) ; x = [h0_cur(1024);h1_prev(1024)]
#define STAGE_PH2(KOFF)                                                         \
    for (int i = tid; i < 512*8; i += NTHR){                                    \
        int kk = i >> 3, bq2 = i & 7;                                           \
        int k = (KOFF) + kk;                                                    \
        float4 v4 = (k < 1024)                                                  \
            ? *(const float4*)&h0T[(size_t)par*32768 + (size_t)k*32 + bq2*4]    \
            : *(const float4*)&h1T[(size_t)(par^1)*32768 + (size_t)(k-1024)*32 + bq2*4]; \
        *(float4*)&xh[kk*33 + bq2*4] = v4;                                      \
    }

// phase-1 GEMM over one chunk: absolute row base A0, NJ iters (wave-strided by 8)
#define GEMM1(A0, NJ) {                                                         \
    _Pragma("unroll 8")                                                         \
    for (int j = 0; j < (NJ); j++){                                             \
        int kk = v + 8*j;                                                       \
        int kg = (A0) + kk;                                                     \
        const float* wrow = (kg < 592) ? W0 + (size_t)kg*G4                     \
                                       : U0 + (size_t)(kg-592)*G4;              \
        float4 w4 = *(const float4*)(wrow + wcol);                              \
        float4 x4 = *(const float4*)&xh[kk*33 + bq*4];                          \
        fma16(acc, w4, x4);                                                     \
    } }

// phase-2 GEMM over one chunk: weight base WB (W1 or U1), local row base C0
#define GEMM2(WB, C0, NJ) {                                                     \
    _Pragma("unroll 8")                                                         \
    for (int j = 0; j < (NJ); j++){                                             \
        int kk = v + 8*j;                                                       \
        float4 w4 = *(const float4*)((WB) + (size_t)((C0)+kk)*G4 + wcol);       \
        float4 x4 = *(const float4*)&xh[kk*33 + bq*4];                          \
        fma16(acc, w4, x4);                                                     \
    } }

// in-block 8-wave reduce of acc tiles -> zbuf[kh][ct*32..+32][b] (coalesced 4KB store)
#define REDUCE_TO_ZBUF() {                                                      \
    __syncthreads();                                                            \
    _Pragma("unroll")                                                           \
    for (int i2 = 0; i2 < 4; i2++){                                             \
        float* zr = &zp[v*1056 + (cq*4+i2)*33 + bq*4];                          \
        *(float4*)zr = make_float4(acc[i2][0],acc[i2][1],acc[i2][2],acc[i2][3]);\
    }                                                                           \
    __syncthreads();                                                            \
    {                                                                           \
        size_t zbase = (size_t)kh*131072 + (size_t)ct*1024;                     \
        for (int o = tid; o < 1024; o += NTHR){                                 \
            int c = o >> 5, b2 = o & 31;                                        \
            float s = 0.f;                                                      \
            _Pragma("unroll")                                                   \
            for (int vv = 0; vv < 8; vv++) s += zp[vv*1056 + c*33 + b2];        \
            zbuf[zbase + o] = s;                                                \
        }                                                                       \
    } }

// gate pass: block owns units 4p..4p+3 ; reads 8 coalesced 128B rows of zbuf
#define GATE(CST, BIAS, HT, WRITE_H1N)                                          \
    if (tid < 128){                                                             \
        int uu = tid >> 5, b2 = tid & 31;                                       \
        int u = (p<<2) + uu;                                                    \
        float z[4];                                                             \
        _Pragma("unroll")                                                       \
        for (int g = 0; g < 4; g++){                                            \
            size_t base = (size_t)(g*1024 + u)*32 + b2;                         \
            z[g] = zbuf[base] + zbuf[131072 + base] + (BIAS)[g*1024 + u];       \
        }                                                                       \
        float cn = fsig(z[1])*(CST)[tid] + fsig(z[0])*ftanh(z[2]);              \
        float hn = fsig(z[3])*ftanh(cn);                                        \
        (CST)[tid] = cn;                                                        \
        (HT)[(size_t)par*32768 + (size_t)u*32 + b2] = hn;                       \
        if (WRITE_H1N) h1N[(size_t)b2*1024 + u] = hn;                           \
    }

// ---------------- persistent recurrence kernel (exclusive full-line weight tiles) -----
__global__ __launch_bounds__(NTHR, 2) void persist(
    const float* __restrict__ enc,   // values [B][TE][ED]
    const float* __restrict__ dec,   // [B][TD][DD]
    const float* __restrict__ keys,  // [B][TE][UN]
    const float* __restrict__ W0, const float* __restrict__ U0, const float* __restrict__ b0v,
    const float* __restrict__ W1, const float* __restrict__ U1, const float* __restrict__ b1v,
    const float* __restrict__ Wq, const float* __restrict__ convk, const float* __restrict__ convb,
    const float* __restrict__ Wloc, const float* __restrict__ v_a, const float* __restrict__ b_a,
    float* __restrict__ h0T,   // [2][1024][32]
    float* __restrict__ h1T,   // [2][1024][32]
    float* __restrict__ h1N,   // [32][1024]
    float* __restrict__ align_,// [B][TE]
    float* __restrict__ denomh,// [TD][B]
    float* __restrict__ ctxacc,// [2][512][32]
    float* __restrict__ zbuf,  // [2][4096][32] k-half z partials
    unsigned* __restrict__ bar,
    float* __restrict__ c_out, float* __restrict__ e_out)
{
    __shared__ __align__(16) float xh[512*33];   // 67.6KB x-staging / zp overlay
    __shared__ float cst0[128], cst1[128];
    __shared__ __align__(16) float invd[32];
    __shared__ __align__(16) float h1s[1024];
    __shared__ float pqp[512];
    __shared__ float pqs[128];
    __shared__ float aw[96];
    __shared__ float fls[50*FLT];
    __shared__ float epart[128];
    __shared__ float alds[64];
    __shared__ float wloc_s[FLT*UN];   // 16KB, kernel-lifetime
    __shared__ float convk_s[KW*FLT];
    __shared__ float convb_s[FLT];
    __shared__ float va_s[UN];
    float* zp = xh;   // overlay: zp[8][1056] = 8448 floats < 16896

    const int tid  = threadIdx.x;
    const int p    = blockIdx.x;
    // GEMM mapping: block owns 32 consecutive cols (full exclusive 128B lines) x K-half
    const int ct   = p >> 1;          // col-tile 0..127 (cols 32ct..32ct+31)
    const int kh   = p & 1;           // k-half
    const int v    = tid >> 6;        // wave = k-slice (stride 8)
    const int lane = tid & 63;
    const int cq   = lane & 7;        // col-quad
    const int bq   = lane >> 3;       // batch-quad
    const int wcol = ct*32 + cq*4;
    // attention mapping
    const int ab   = p >> 3;
    const int ach  = p & 7;
    const int t0a  = ach*50;

    if (tid < 128){ cst0[tid] = 0.f; cst1[tid] = 0.f; }
    for (int i = tid; i < FLT*UN; i += NTHR) wloc_s[i] = Wloc[i];
    for (int i = tid; i < KW*FLT; i += NTHR) convk_s[i] = convk[i];
    if (tid < FLT) convb_s[tid] = convb[tid];
    if (tid >= 64 && tid < 64+UN) va_s[tid-64] = v_a[tid-64];
    unsigned epoch = 0;
    unsigned* cntp = bar;
    unsigned* genp = bar + 32;
    __syncthreads();

    for (int t = 0; t < TD; t++){
        const int par = t & 1;
        //=============== phase 1 GEMM: z0 partials (K-half = 808 = 512+296) ===============
        if (tid < 32) invd[tid] = (t>0) ? 1.f/denomh[(size_t)(t-1)*32 + tid] : 0.f;
        __syncthreads();
        {
            const int khb = kh*808;
            float acc[4][4];
#pragma unroll
            for (int i=0;i<4;i++)
#pragma unroll
                for (int j=0;j<4;j++) acc[i][j] = 0.f;
            STAGE_PH1(khb, 512)     __syncthreads();
            GEMM1(khb, 64)          __syncthreads();
            STAGE_PH1(khb+512, 296) __syncthreads();
            GEMM1(khb+512, 37)
            REDUCE_TO_ZBUF()
        }
        gridbar(cntp, genp, epoch);   // A: zbuf(z0) complete

        //=============== gate 0 (h0) + housekeeping ===============
        GATE(cst0, b0v, h0T, 0)
        if (t > 0){
            if (tid >= 128 && tid < 178){
                int jj = tid - 128;
                float idn = 1.f / denomh[(size_t)(t-1)*32 + ab];
                align_[(size_t)ab*TE + t0a + jj] +=
                    e_out[((size_t)ab*TD + (t-1))*TE + t0a + jj] * idn;
            }
            if (p < 32){
                float idn = 1.f / denomh[(size_t)(t-1)*32 + p];
                size_t ci = (size_t)(par^1)*16384 + (size_t)tid*32 + p;
                float vv = ctxacc[ci];
                c_out[((size_t)p*TD + (t-1))*ED + tid] = vv * idn;
                ctxacc[ci] = 0.f;
            }
        }
        gridbar(cntp, genp, epoch);   // B: h0 ready

        //=============== phase 2 GEMM: z1 partials (K-half = 1024 = 512+512) ===============
        {
            const float* WB = kh ? U1 : W1;
            const int khb = kh*1024;
            float acc[4][4];
#pragma unroll
            for (int i=0;i<4;i++)
#pragma unroll
                for (int j=0;j<4;j++) acc[i][j] = 0.f;
            STAGE_PH2(khb)     __syncthreads();
            GEMM2(WB, 0, 64)   __syncthreads();
            STAGE_PH2(khb+512) __syncthreads();
            GEMM2(WB, 512, 64)
            REDUCE_TO_ZBUF()
        }
        gridbar(cntp, genp, epoch);   // C: zbuf(z1) complete

        //=============== gate 1 (h1) ===============
        GATE(cst1, b1v, h1T, 1)
        gridbar(cntp, genp, epoch);   // D: h1 ready

        //=============== attention ===============
        if (tid < 256) *(float4*)&h1s[tid*4] = *(const float4*)&h1N[(size_t)ab*1024 + tid*4];
        if (tid >= 256 && tid < 336){
            int jj = tid - 256;
            int pp = t0a + jj - 15;
            aw[jj] = (pp >= 0 && pp < TE) ? align_[(size_t)ab*TE + pp] : 0.f;
        }
        __syncthreads();
        {
            int u = tid & 127, kq = tid >> 7;
            float s = 0.f;
#pragma unroll 8
            for (int k = kq*256; k < kq*256+256; k++)
                s += h1s[k] * Wq[(size_t)k*UN + u];
            pqp[kq*128 + u] = s;
        }
        for (int o = tid; o < 50*FLT; o += NTHR){
            int pos = o >> 5, fl = o & 31;
            float s = convb_s[fl];
#pragma unroll
            for (int k=0;k<KW;k++) s += aw[pos+k]*convk_s[k*FLT+fl];
            fls[o] = s;
        }
        __syncthreads();
        if (tid < 128) pqs[tid] = pqp[tid] + pqp[128+tid] + pqp[256+tid] + pqp[384+tid] + b_a[tid];
        __syncthreads();
        for (int o = tid; o < 50*UN; o += NTHR){
            int pos = o >> 7, u = o & 127;
            float loc = 0.f;
            const float* fr = &fls[pos*FLT];
#pragma unroll
            for (int fl=0; fl<FLT; fl++) loc += fr[fl]*wloc_s[fl*UN+u];
            float x = keys[((size_t)ab*TE + t0a + pos)*UN + u] + pqs[u] + loc;
            float val = va_s[u]*ftanh(x);
            val += __shfl_down(val, 32, 64);
            val += __shfl_down(val, 16, 64);
            val += __shfl_down(val,  8, 64);
            val += __shfl_down(val,  4, 64);
            val += __shfl_down(val,  2, 64);
            val += __shfl_down(val,  1, 64);
            if ((tid & 63) == 0) epart[o >> 6] = val;
        }
        __syncthreads();
        if (tid < 50){
            float e = epart[tid*2] + epart[tid*2+1];
            float ex = __expf(e);   // |e| small: max-free softmax safe
            e_out[((size_t)ab*TD + t)*TE + t0a + tid] = ex;   // unnormalized
            alds[tid] = ex;
        }
        __syncthreads();
        if (tid == 0){
            float s = 0.f;
#pragma unroll
            for (int i=0;i<50;i++) s += alds[i];
            atomicAdd(&denomh[(size_t)t*32 + ab], s);
        }
        {
            const float* vb = enc + ((size_t)ab*TE + t0a)*ED;
            float a2 = 0.f;
#pragma unroll 10
            for (int pp=0; pp<50; pp++) a2 += alds[pp]*vb[(size_t)pp*ED + tid];
            atomicAdd(&ctxacc[(size_t)par*16384 + (size_t)tid*32 + ab], a2);
        }
        gridbar(cntp, genp, epoch);   // E: step complete
    }
}

// ---------------- final normalization ----------------
__global__ void norm_e_kernel(const float* __restrict__ denomh, float* __restrict__ e_out)
{
    size_t idx = (size_t)blockIdx.x*512 + threadIdx.x;
    int b = (int)(idx / ((size_t)TD*TE));
    int r = (int)(idx % ((size_t)TD*TE));
    int t = r / TE;
    e_out[idx] = e_out[idx] / denomh[(size_t)t*B + b];
}

__global__ void norm_c_last(const float* __restrict__ denomh, const float* __restrict__ ctxacc1,
                            float* __restrict__ c_out)
{
    int b = blockIdx.x; int d = threadIdx.x;   // 32 blocks x 512
    c_out[((size_t)b*TD + (TD-1))*ED + d] =
        ctxacc1[(size_t)d*32 + b] / denomh[(size_t)(TD-1)*B + b];
}

extern "C" void kernel_launch(void* const* d_in, const int* in_sizes, int n_in,
                              void* d_out, int out_size, void* d_ws, size_t ws_size,
                              hipStream_t stream)
{
    const float* enc   = (const float*)d_in[0];
    const float* dec   = (const float*)d_in[1];
    const float* Wm    = (const float*)d_in[2];
    const float* Wq    = (const float*)d_in[3];
    const float* convk = (const float*)d_in[4];
    const float* convb = (const float*)d_in[5];
    const float* Wloc  = (const float*)d_in[6];
    const float* v_a   = (const float*)d_in[7];
    const float* b_a   = (const float*)d_in[8];
    const float* W0    = (const float*)d_in[9];
    const float* U0    = (const float*)d_in[10];
    const float* b0    = (const float*)d_in[11];
    const float* W1    = (const float*)d_in[12];
    const float* U1    = (const float*)d_in[13];
    const float* b1    = (const float*)d_in[14];

    float* out   = (float*)d_out;
    float* c_out = out;                                  // [B, TD, ED]
    float* e_out = out + (size_t)B*TD*ED;                // [B, TD, TE]

    // workspace budget is 16MB (rounds 4/6 exceeded it -> container faults).
    // Total here: ~8.6 MB.
    float* ws     = (float*)d_ws;
    float* h0T    = ws;                                  // 2*1024*32 = 65536
    float* h1T    = h0T + 65536;                         // 65536
    float* h1N    = h1T + 65536;                         // 32768
    float* align_ = h1N + 32768;                         // 12800
    float* denomh = align_ + 12800;                      // 25600
    float* ctxacc = denomh + 25600;                      // 32768
    unsigned* bar = (unsigned*)(ctxacc + 32768);         // 64 uints
    float* zbuf   = (float*)(bar + 64);                  // 2*4096*32 = 262144
    float* keys   = zbuf + 262144;                       // 1,638,400
    // end: 2,143,552 floats + 64 uints  (~8.6 MB)

    // zero recurrent state + alignment + denominators + ctxacc + barrier
    hipMemsetAsync(ws, 0,
        (size_t)(65536 + 65536 + 32768 + 12800 + 25600 + 32768)*sizeof(float)
        + 64*sizeof(unsigned), stream);

    keys_kernel<<<dim3(B,50), 128, 0, stream>>>(enc, Wm, keys);

    persist<<<NBLK, NTHR, 0, stream>>>(enc, dec, keys,
                                       W0, U0, b0, W1, U1, b1,
                                       Wq, convk, convb, Wloc, v_a, b_a,
                                       h0T, h1T, h1N, align_, denomh, ctxacc, zbuf, bar,
                                       c_out, e_out);

    norm_e_kernel<<<(B*TD*TE)/512, 512, 0, stream>>>(denomh, e_out);
    norm_c_last<<<32, 512, 0, stream>>>(denomh, ctxacc + 16384, c_out);
}